// Round 1
// baseline (639.091 us; speedup 1.0000x reference)
//
#include <hip/hip_runtime.h>
#include <hip/hip_bf16.h>
#include <stdint.h>

#define B_ 4
#define S_ 1024
#define D_ 1024
#define H_ 4096
#define E_ 8
#define T_ (B_*S_)   // 4096 tokens

typedef __bf16 bf16x8 __attribute__((ext_vector_type(8)));
typedef float f32x4 __attribute__((ext_vector_type(4)));
typedef unsigned short ushort8 __attribute__((ext_vector_type(8)));

__device__ __forceinline__ unsigned short f2bf(float f) {
  union { float f; uint32_t u; } v; v.f = f;
  uint32_t u = v.u;
  u += 0x7fff + ((u >> 16) & 1);   // round-to-nearest-even
  return (unsigned short)(u >> 16);
}

// ---------------- gating: scores + top-2 routing ----------------
__global__ __launch_bounds__(256) void gating_kernel(
    const float* __restrict__ x, const float* __restrict__ Wg,
    const float* __restrict__ bg, float* __restrict__ scores,
    int* __restrict__ cnt, int* __restrict__ lists) {
  int t = blockIdx.x * 4 + (threadIdx.x >> 6);
  int l = threadIdx.x & 63;
  float acc[E_];
#pragma unroll
  for (int e = 0; e < E_; ++e) acc[e] = 0.f;
  const float* xr = x + (size_t)t * D_;
  for (int k = l; k < D_; k += 64) {
    float xv = xr[k];
    const float4* w = (const float4*)(Wg + (size_t)k * E_);
    float4 w0 = w[0], w1 = w[1];
    acc[0] += xv * w0.x; acc[1] += xv * w0.y; acc[2] += xv * w0.z; acc[3] += xv * w0.w;
    acc[4] += xv * w1.x; acc[5] += xv * w1.y; acc[6] += xv * w1.z; acc[7] += xv * w1.w;
  }
#pragma unroll
  for (int off = 32; off > 0; off >>= 1)
#pragma unroll
    for (int e = 0; e < E_; ++e) acc[e] += __shfl_xor(acc[e], off, 64);
  if (l == 0) {
    float s[E_];
#pragma unroll
    for (int e = 0; e < E_; ++e) {
      s[e] = acc[e] + bg[e];
      scores[(size_t)t * E_ + e] = s[e];
    }
    int i1 = 0; float m1 = -1e30f;
#pragma unroll
    for (int e = 0; e < E_; ++e) if (s[e] > m1) { m1 = s[e]; i1 = e; }
    int i2 = -1; float m2 = -1e30f;
#pragma unroll
    for (int e = 0; e < E_; ++e) if (e != i1 && s[e] > m2) { m2 = s[e]; i2 = e; }
    int p1 = atomicAdd(&cnt[i1], 1); lists[i1 * T_ + p1] = t;
    int p2 = atomicAdd(&cnt[i2], 1); lists[i2 * T_ + p2] = t;
  }
}

__global__ void scan_kernel(const int* __restrict__ cnt, int* __restrict__ off) {
  if (threadIdx.x == 0) {
    int o = 0;
    for (int e = 0; e < E_; ++e) { off[e] = o; o += cnt[e]; }
  }
}

// ---------------- grouped per-expert GEMM ----------------
#define BM 128
#define BN 128
#define BK 64
#define PAD 8
#define LDK (BK + PAD)   // 72 halfwords per row

template <int LAYER>
__global__ __launch_bounds__(256) void ffn_gemm(
    const float* __restrict__ x,              // [T,D] fp32 (layer1 A src)
    const unsigned short* __restrict__ hbuf,  // [8192,H] bf16 (layer2 A src)
    const float* __restrict__ W,              // W1 [E,D,H] or W2 [E,H,D]
    const float* __restrict__ bias,           // b1 [E,H] or b2 [E,D]
    const int* __restrict__ cnt, const int* __restrict__ off,
    const int* __restrict__ lists,
    unsigned short* __restrict__ hout,        // layer1 out (bf16 h)
    float* __restrict__ out)                  // layer2 out [T,D] fp32
{
  constexpr int K = (LAYER == 1) ? D_ : H_;
  constexpr int N = (LAYER == 1) ? H_ : D_;
  const int e  = blockIdx.z;
  const int m0 = blockIdx.y * BM;
  const int n0 = blockIdx.x * BN;
  const int count = cnt[e];
  if (m0 >= count) return;
  const int oe = off[e];
  const int* lst = lists + e * T_;

  __shared__ unsigned short sA[BM][LDK];
  __shared__ unsigned short sB[BN][LDK];

  const int tid  = threadIdx.x;
  const int lane = tid & 63;
  const int wv   = tid >> 6;
  const int wm   = (wv >> 1) * 64, wn = (wv & 1) * 64;
  const int lrow = lane & 15;
  const int kg   = lane >> 4;

  // A staging: row ar = tid>>1, k-half ak = (tid&1)*32
  const int ar = tid >> 1;
  const int ak = (tid & 1) * 32;
  const bool avalid = (m0 + ar) < count;
  const float* asrc_f = nullptr;
  const unsigned short* asrc_h = nullptr;
  if (LAYER == 1) {
    int tok = avalid ? lst[m0 + ar] : 0;
    asrc_f = x + (size_t)tok * D_;
  } else {
    int row = avalid ? (oe + m0 + ar) : 0;
    asrc_h = hbuf + (size_t)row * H_;
  }
  // B staging: col bn = tid&127, k-group bkg = (tid>>7)*32
  const int bn  = tid & 127;
  const int bkg = (tid >> 7) * 32;
  const float* bsrc = W + (size_t)e * K * N + n0 + bn;

  f32x4 acc[4][4];
#pragma unroll
  for (int i = 0; i < 4; ++i)
#pragma unroll
    for (int j = 0; j < 4; ++j) acc[i][j] = (f32x4){0.f, 0.f, 0.f, 0.f};

  for (int kt = 0; kt < K; kt += BK) {
    // ---- stage A tile [BM][BK] ----
    if (LAYER == 1) {
      const float4* src = (const float4*)(asrc_f + kt + ak);
#pragma unroll
      for (int i = 0; i < 8; i += 2) {
        float4 v0 = src[i], v1 = src[i + 1];
        ushort8 w;
        w[0]=f2bf(v0.x); w[1]=f2bf(v0.y); w[2]=f2bf(v0.z); w[3]=f2bf(v0.w);
        w[4]=f2bf(v1.x); w[5]=f2bf(v1.y); w[6]=f2bf(v1.z); w[7]=f2bf(v1.w);
        *(ushort8*)&sA[ar][ak + i * 4] = w;
      }
    } else {
      const ushort8* src = (const ushort8*)(asrc_h + kt + ak);
#pragma unroll
      for (int i = 0; i < 4; ++i)
        *(ushort8*)&sA[ar][ak + i * 8] = src[i];
    }
    // ---- stage B tile transposed: sB[n][k] ----
    {
#pragma unroll
      for (int i = 0; i < 4; ++i) {
        ushort8 w;
#pragma unroll
        for (int j = 0; j < 8; ++j)
          w[j] = f2bf(bsrc[(size_t)(kt + bkg + i * 8 + j) * N]);
        *(ushort8*)&sB[bn][bkg + i * 8] = w;
      }
    }
    __syncthreads();
#pragma unroll
    for (int ks = 0; ks < BK; ks += 32) {
      bf16x8 af[4], bfr[4];
#pragma unroll
      for (int i = 0; i < 4; ++i) {
        af[i]  = *(const bf16x8*)&sA[wm + i * 16 + lrow][ks + kg * 8];
        bfr[i] = *(const bf16x8*)&sB[wn + i * 16 + lrow][ks + kg * 8];
      }
#pragma unroll
      for (int i = 0; i < 4; ++i)
#pragma unroll
        for (int j = 0; j < 4; ++j)
          acc[i][j] = __builtin_amdgcn_mfma_f32_16x16x32_bf16(af[i], bfr[j], acc[i][j], 0, 0, 0);
    }
    __syncthreads();
  }

  // ---- epilogue ----
  const int rbase = 4 * kg;
#pragma unroll
  for (int i = 0; i < 4; ++i) {
#pragma unroll
    for (int r = 0; r < 4; ++r) {
      int row  = wm + i * 16 + rbase + r;
      int grow = m0 + row;
      if (grow < count) {
#pragma unroll
        for (int j = 0; j < 4; ++j) {
          int col  = wn + j * 16 + lrow;
          int gcol = n0 + col;
          float v = acc[i][j][r] + bias[(size_t)e * N + gcol];
          if (LAYER == 1) {
            v = v > 0.f ? v : 0.f;
            hout[(size_t)(oe + grow) * H_ + gcol] = f2bf(v);
          } else {
            int tok = lst[grow];
            atomicAdd(&out[(size_t)tok * D_ + gcol], v);
          }
        }
      }
    }
  }
}

extern "C" void kernel_launch(void* const* d_in, const int* in_sizes, int n_in,
                              void* d_out, int out_size, void* d_ws, size_t ws_size,
                              hipStream_t stream) {
  (void)in_sizes; (void)n_in; (void)out_size; (void)ws_size;
  const float* x  = (const float*)d_in[0];
  const float* W1 = (const float*)d_in[1];
  const float* b1 = (const float*)d_in[2];
  const float* W2 = (const float*)d_in[3];
  const float* b2 = (const float*)d_in[4];
  const float* Wg = (const float*)d_in[5];
  const float* bg = (const float*)d_in[6];

  float* out    = (float*)d_out;               // [T,D]
  float* scores = out + (size_t)T_ * D_;       // [T,E]

  char* ws = (char*)d_ws;
  int* cnt   = (int*)ws;                        // 8 ints
  int* off   = (int*)(ws + 32);                 // 8 ints
  int* lists = (int*)(ws + 64);                 // 8*4096 ints = 128 KB
  unsigned short* hbuf = (unsigned short*)(ws + 64 + 4 * E_ * T_);  // [8192,H] bf16, 64 MB

  hipMemsetAsync(out, 0, (size_t)T_ * D_ * sizeof(float), stream);
  hipMemsetAsync(cnt, 0, 64, stream);

  gating_kernel<<<T_ / 4, 256, 0, stream>>>(x, Wg, bg, scores, cnt, lists);
  scan_kernel<<<1, 64, 0, stream>>>(cnt, off);

  ffn_gemm<1><<<dim3(H_ / BN, T_ / BM, E_), 256, 0, stream>>>(
      x, hbuf, W1, b1, cnt, off, lists, hbuf, nullptr);
  ffn_gemm<2><<<dim3(D_ / BN, T_ / BM, E_), 256, 0, stream>>>(
      x, hbuf, W2, b2, cnt, off, lists, nullptr, out);
}

// Round 2
// 516.006 us; speedup vs baseline: 1.2385x; 1.2385x over previous
//
#include <hip/hip_runtime.h>
#include <hip/hip_bf16.h>
#include <stdint.h>

#define B_ 4
#define S_ 1024
#define D_ 1024
#define H_ 4096
#define E_ 8
#define T_ (B_*S_)   // 4096 tokens

#define BM 128
#define BN 128
#define BK 64        // 128 bytes of bf16 per row per tile

typedef __bf16 bf16x8 __attribute__((ext_vector_type(8)));
typedef float f32x4 __attribute__((ext_vector_type(4)));
typedef unsigned short ushort8 __attribute__((ext_vector_type(8)));

__device__ __forceinline__ unsigned short f2bf(float f) {
  union { float f; uint32_t u; } v; v.f = f;
  uint32_t u = v.u;
  u += 0x7fff + ((u >> 16) & 1);   // round-to-nearest-even
  return (unsigned short)(u >> 16);
}

// async global->LDS, 16B per lane; LDS dest is WAVE-UNIFORM base, HW scatters lane*16
__device__ __forceinline__ void gl16(const void* g, void* l) {
  __builtin_amdgcn_global_load_lds(
      (const __attribute__((address_space(1))) void*)g,
      (__attribute__((address_space(3))) void*)l,
      16, 0, 0);
}

// ---------------- x fp32 -> bf16 ----------------
__global__ __launch_bounds__(256) void conv_x_kernel(
    const float* __restrict__ x, unsigned short* __restrict__ xb) {
  size_t i = ((size_t)blockIdx.x * 256 + threadIdx.x) * 8;
  const float4* s = (const float4*)(x + i);
  float4 v0 = s[0], v1 = s[1];
  ushort8 w;
  w[0]=f2bf(v0.x); w[1]=f2bf(v0.y); w[2]=f2bf(v0.z); w[3]=f2bf(v0.w);
  w[4]=f2bf(v1.x); w[5]=f2bf(v1.y); w[6]=f2bf(v1.z); w[7]=f2bf(v1.w);
  *(ushort8*)(xb + i) = w;
}

// ---------------- W fp32 [E][R][C] -> bf16 [E][C][R] ----------------
__global__ __launch_bounds__(256) void transpose_conv(
    const float* __restrict__ in, unsigned short* __restrict__ outp,
    int R, int C) {
  __shared__ float tile[64][68];   // pad 68: float4-store aligned, reads 4-way worst
  const int e = blockIdx.z;
  const size_t eoff = (size_t)e * R * C;
  const int r0 = blockIdx.y * 64, c0 = blockIdx.x * 64;
  const int t = threadIdx.x;
  {
    const int r = t >> 2, cq = (t & 3) * 16;
    const float4* s4 = (const float4*)(in + eoff + (size_t)(r0 + r) * C + (c0 + cq));
#pragma unroll
    for (int i = 0; i < 4; ++i)
      *(float4*)&tile[r][cq + i * 4] = s4[i];
  }
  __syncthreads();
  {
    const int c = t >> 2, r8 = (t & 3) * 16;
    unsigned short* dst = outp + eoff + (size_t)(c0 + c) * R + (r0 + r8);
    ushort8 w0, w1;
#pragma unroll
    for (int j = 0; j < 8; ++j) {
      w0[j] = f2bf(tile[r8 + j][c]);
      w1[j] = f2bf(tile[r8 + 8 + j][c]);
    }
    *(ushort8*)dst = w0;
    *(ushort8*)(dst + 8) = w1;
  }
}

// ---------------- gating: scores + top-2 routing ----------------
__global__ __launch_bounds__(256) void gating_kernel(
    const float* __restrict__ x, const float* __restrict__ Wg,
    const float* __restrict__ bg, float* __restrict__ scores,
    int* __restrict__ cnt, int* __restrict__ lists) {
  int t = blockIdx.x * 4 + (threadIdx.x >> 6);
  int l = threadIdx.x & 63;
  float acc[E_];
#pragma unroll
  for (int e = 0; e < E_; ++e) acc[e] = 0.f;
  const float* xr = x + (size_t)t * D_;
  for (int k = l; k < D_; k += 64) {
    float xv = xr[k];
    const float4* w = (const float4*)(Wg + (size_t)k * E_);
    float4 w0 = w[0], w1 = w[1];
    acc[0] += xv * w0.x; acc[1] += xv * w0.y; acc[2] += xv * w0.z; acc[3] += xv * w0.w;
    acc[4] += xv * w1.x; acc[5] += xv * w1.y; acc[6] += xv * w1.z; acc[7] += xv * w1.w;
  }
#pragma unroll
  for (int off = 32; off > 0; off >>= 1)
#pragma unroll
    for (int e = 0; e < E_; ++e) acc[e] += __shfl_xor(acc[e], off, 64);
  if (l == 0) {
    float s[E_];
#pragma unroll
    for (int e = 0; e < E_; ++e) {
      s[e] = acc[e] + bg[e];
      scores[(size_t)t * E_ + e] = s[e];
    }
    int i1 = 0; float m1 = -1e30f;
#pragma unroll
    for (int e = 0; e < E_; ++e) if (s[e] > m1) { m1 = s[e]; i1 = e; }
    int i2 = -1; float m2 = -1e30f;
#pragma unroll
    for (int e = 0; e < E_; ++e) if (e != i1 && s[e] > m2) { m2 = s[e]; i2 = e; }
    int p1 = atomicAdd(&cnt[i1], 1); lists[i1 * T_ + p1] = t;
    int p2 = atomicAdd(&cnt[i2], 1); lists[i2 * T_ + p2] = t;
  }
}

__global__ void scan_kernel(const int* __restrict__ cnt, int* __restrict__ off) {
  if (threadIdx.x == 0) {
    int o = 0;
    for (int e = 0; e < E_; ++e) { off[e] = o; o += cnt[e]; }
  }
}

// ---------------- grouped per-expert GEMM (m97 structure) ----------------
// A: bf16 rows gathered (L1: xb via token list; L2: hbuf linear)
// B: WT bf16 [E][N][K] rows
// LDS image: [row][64k] bf16, 128B/row, k-bytes XOR-swizzled by ((row&7)<<4).
// Swizzle baked into per-lane GLOBAL source addr (gload_lds writes linearly).
template <int LAYER>
__global__ __launch_bounds__(256) void ffn_gemm(
    const unsigned short* __restrict__ xb,
    const unsigned short* __restrict__ hbuf,
    const unsigned short* __restrict__ WT,
    const float* __restrict__ bias,
    const int* __restrict__ cnt, const int* __restrict__ off,
    const int* __restrict__ lists,
    unsigned short* __restrict__ hout,
    float* __restrict__ out)
{
  constexpr int K = (LAYER == 1) ? D_ : H_;
  constexpr int N = (LAYER == 1) ? H_ : D_;
  const int e  = blockIdx.z;
  const int m0 = blockIdx.y * BM;
  const int n0 = blockIdx.x * BN;
  const int count = cnt[e];
  if (m0 >= count) return;
  const int oe = off[e];
  const int* lst = lists + e * T_;

  __shared__ unsigned short sA[BM * BK];   // 16 KB
  __shared__ unsigned short sB[BN * BK];   // 16 KB

  const int tid  = threadIdx.x;
  const int lane = tid & 63;
  const int wv   = tid >> 6;
  const int wm   = (wv >> 1) * 64, wn = (wv & 1) * 64;

  // staging: per wave 4 issues each for A and B; issue i covers rows wv*32+i*8 .. +7
  const int srow = lane >> 3;              // 0..7  (row within issue)
  const int schunk = (lane & 7) * 16;      // byte chunk within 128B row
  const int sgoff = schunk ^ (srow << 4);  // swizzled source byte offset

  const char* arow[4];
  const char* brow[4];
#pragma unroll
  for (int i = 0; i < 4; ++i) {
    int r  = wv * 32 + i * 8 + srow;
    int gr = m0 + r;
    if (LAYER == 1) {
      int tok = (gr < count) ? lst[gr] : lst[m0];
      arow[i] = (const char*)(xb + (size_t)tok * K);
    } else {
      int rr = (gr < count) ? gr : m0;
      arow[i] = (const char*)(hbuf + (size_t)(oe + rr) * K);
    }
    brow[i] = (const char*)(WT + (size_t)e * N * K + (size_t)(n0 + r) * K);
  }

  // fragment addressing
  const int lrow = lane & 15;
  const int kg   = lane >> 4;
  const int fswz = (lrow & 7) << 4;

  f32x4 acc[4][4];
#pragma unroll
  for (int i = 0; i < 4; ++i)
#pragma unroll
    for (int j = 0; j < 4; ++j) acc[i][j] = (f32x4){0.f, 0.f, 0.f, 0.f};

  for (int kt = 0; kt < K; kt += BK) {
    const int kb = kt * 2;
#pragma unroll
    for (int i = 0; i < 4; ++i) {
      gl16(arow[i] + kb + sgoff, (char*)sA + (wv * 32 + i * 8) * 128);
      gl16(brow[i] + kb + sgoff, (char*)sB + (wv * 32 + i * 8) * 128);
    }
    __syncthreads();
#pragma unroll
    for (int ks = 0; ks < 2; ++ks) {
      bf16x8 af[4], bfm[4];
      const int kbyte = ks * 64 + kg * 16;
#pragma unroll
      for (int i = 0; i < 4; ++i) {
        int ra = wm + i * 16 + lrow;
        int rb = wn + i * 16 + lrow;
        af[i]  = *(const bf16x8*)((const char*)sA + ra * 128 + (kbyte ^ fswz));
        bfm[i] = *(const bf16x8*)((const char*)sB + rb * 128 + (kbyte ^ fswz));
      }
#pragma unroll
      for (int i = 0; i < 4; ++i)
#pragma unroll
        for (int j = 0; j < 4; ++j)
          acc[i][j] = __builtin_amdgcn_mfma_f32_16x16x32_bf16(af[i], bfm[j], acc[i][j], 0, 0, 0);
    }
    __syncthreads();
  }

  // ---- epilogue ----
  const int rbase = 4 * kg;
#pragma unroll
  for (int i = 0; i < 4; ++i) {
#pragma unroll
    for (int r = 0; r < 4; ++r) {
      int row  = wm + i * 16 + rbase + r;
      int grow = m0 + row;
      if (grow < count) {
#pragma unroll
        for (int j = 0; j < 4; ++j) {
          int col  = wn + j * 16 + lrow;
          int gcol = n0 + col;
          float v = acc[i][j][r] + bias[(size_t)e * N + gcol];
          if (LAYER == 1) {
            v = v > 0.f ? v : 0.f;
            hout[(size_t)(oe + grow) * H_ + gcol] = f2bf(v);
          } else {
            int tok = lst[grow];
            atomicAdd(&out[(size_t)tok * D_ + gcol], v);
          }
        }
      }
    }
  }
}

extern "C" void kernel_launch(void* const* d_in, const int* in_sizes, int n_in,
                              void* d_out, int out_size, void* d_ws, size_t ws_size,
                              hipStream_t stream) {
  (void)in_sizes; (void)n_in; (void)out_size; (void)ws_size;
  const float* x  = (const float*)d_in[0];
  const float* W1 = (const float*)d_in[1];
  const float* b1 = (const float*)d_in[2];
  const float* W2 = (const float*)d_in[3];
  const float* b2 = (const float*)d_in[4];
  const float* Wg = (const float*)d_in[5];
  const float* bg = (const float*)d_in[6];

  float* out    = (float*)d_out;               // [T,D]
  float* scores = out + (size_t)T_ * D_;       // [T,E]

  char* ws = (char*)d_ws;
  int* cnt   = (int*)ws;                                  // 32 B
  int* off   = (int*)(ws + 32);                           // 32 B
  int* lists = (int*)(ws + 64);                           // 128 KB
  unsigned short* xb   = (unsigned short*)(ws + 131200);              // 8 MB
  unsigned short* hbuf = (unsigned short*)(ws + 131200 + 8388608);    // 64 MB [8192][4096]
  unsigned short* WT   = (unsigned short*)(ws + 131200 + 8388608 + 67108864); // 64 MB shared W1T/W2T

  hipMemsetAsync(out, 0, (size_t)T_ * D_ * sizeof(float), stream);
  hipMemsetAsync(cnt, 0, 64, stream);

  conv_x_kernel<<<(T_ * D_) / (256 * 8), 256, 0, stream>>>(x, xb);
  gating_kernel<<<T_ / 4, 256, 0, stream>>>(x, Wg, bg, scores, cnt, lists);
  scan_kernel<<<1, 64, 0, stream>>>(cnt, off);

  // W1 [E,1024,4096] -> W1T [E,4096,1024]
  transpose_conv<<<dim3(H_ / 64, D_ / 64, E_), 256, 0, stream>>>(W1, WT, D_, H_);
  ffn_gemm<1><<<dim3(H_ / BN, T_ / BM, E_), 256, 0, stream>>>(
      xb, hbuf, WT, b1, cnt, off, lists, hbuf, nullptr);

  // W2 [E,4096,1024] -> W2T [E,1024,4096]  (reuses WT after gemm1)
  transpose_conv<<<dim3(D_ / 64, H_ / 64, E_), 256, 0, stream>>>(W2, WT, H_, D_);
  ffn_gemm<2><<<dim3(D_ / BN, T_ / BM, E_), 256, 0, stream>>>(
      xb, hbuf, WT, b2, cnt, off, lists, nullptr, out);
}